// Round 12
// baseline (2640.822 us; speedup 1.0000x reference)
//
#include <hip/hip_runtime.h>
#include <math.h>

#define SEQ   2048
#define BATCH 64
#define IN    256
#define HID   256

typedef _Float16 hf2 __attribute__((ext_vector_type(2)));
typedef _Float16 hf4 __attribute__((ext_vector_type(4)));
typedef _Float16 hf8 __attribute__((ext_vector_type(8)));
typedef float    f32x4 __attribute__((ext_vector_type(4)));

static __device__ __forceinline__ float fast_sigmoid(float x) {
    return __builtin_amdgcn_rcpf(1.0f + __expf(-x));
}

static __device__ __forceinline__ float fast_tanh(float x) {
    // tanh(x) = 2/(1+exp(-2x)) - 1
    const float e = __expf(-2.0f * x);
    return fmaf(2.0f, __builtin_amdgcn_rcpf(1.0f + e), -1.0f);
}

static __device__ __forceinline__ hf8 cvt8(const float4& a, const float4& b) {
    hf8 f;
    f[0] = (_Float16)a.x; f[1] = (_Float16)a.y;
    f[2] = (_Float16)a.z; f[3] = (_Float16)a.w;
    f[4] = (_Float16)b.x; f[5] = (_Float16)b.y;
    f[6] = (_Float16)b.z; f[7] = (_Float16)b.w;
    return f;
}

// ---------------------------------------------------------------------------
// Kernel 0: Wz,Wh fp32 -> W16 [512][256] fp16 (rows 0-255 = Wz, 256-511 = Wh)
// ---------------------------------------------------------------------------
__global__ __launch_bounds__(256) void w16_kernel(
    const float* __restrict__ Wz, const float* __restrict__ Wh,
    _Float16* __restrict__ W16)
{
    const int idx = blockIdx.x * 256 + threadIdx.x;
    const int row = idx >> 8;
    const int col = idx & 255;
    const float v = (row < 256) ? Wz[row * 256 + col] : Wh[(row - 256) * 256 + col];
    W16[idx] = (_Float16)v;
}

// ---------------------------------------------------------------------------
// Kernel A: input projections via mfma_f32_16x16x32_f16 (validated R4+).
// xz+bz+cz -> xz16 (fp16, d_ws); xh+bh+ch -> d_out fp32 (consumed by rec).
// ---------------------------------------------------------------------------
__global__ __launch_bounds__(256) void proj_mfma_kernel(
    const float* __restrict__ x,
    const _Float16* __restrict__ W16,
    const float* __restrict__ bz, const float* __restrict__ cz,
    const float* __restrict__ bh, const float* __restrict__ ch,
    _Float16* __restrict__ xz16,
    float* __restrict__ xh_out)
{
    const int tid  = threadIdx.x;
    const int lane = tid & 63;
    const int w    = tid >> 6;
    const int m0   = blockIdx.x * 16;
    const int col0 = w * 128;

    const int r = lane & 15;
    const int g = lane >> 4;

    f32x4 acc[8] = {f32x4{0,0,0,0}, f32x4{0,0,0,0}, f32x4{0,0,0,0}, f32x4{0,0,0,0},
                    f32x4{0,0,0,0}, f32x4{0,0,0,0}, f32x4{0,0,0,0}, f32x4{0,0,0,0}};

    const float*    xrow  = x   + (size_t)(m0 + r) * IN + g * 8;
    const _Float16* wbase = W16 + (size_t)(col0 + r) * IN + g * 8;

#pragma unroll
    for (int kt = 0; kt < 8; ++kt) {
        const float4 xa = *reinterpret_cast<const float4*>(xrow + kt * 32);
        const float4 xb = *reinterpret_cast<const float4*>(xrow + kt * 32 + 4);
        const hf8 a = cvt8(xa, xb);
#pragma unroll
        for (int t = 0; t < 8; ++t) {
            const hf8 bfrag = *reinterpret_cast<const hf8*>(
                wbase + (size_t)t * 16 * IN + kt * 32);
            acc[t] = __builtin_amdgcn_mfma_f32_16x16x32_f16(a, bfrag, acc[t], 0, 0, 0);
        }
    }

    if (w < 2) {
#pragma unroll
        for (int t = 0; t < 8; ++t) {
            const int c = col0 + t * 16 + r;
            const float bsum = bz[c] + cz[c];
#pragma unroll
            for (int reg = 0; reg < 4; ++reg) {
                const int m = m0 + 4 * g + reg;
                xz16[(size_t)m * HID + c] = (_Float16)(acc[t][reg] + bsum);
            }
        }
    } else {
#pragma unroll
        for (int t = 0; t < 8; ++t) {
            const int c = col0 - 256 + t * 16 + r;
            const float bsum = bh[c] + ch[c];
#pragma unroll
            for (int reg = 0; reg < 4; ++reg) {
                const int m = m0 + 4 * g + reg;
                xh_out[(size_t)m * HID + c] = acc[t][reg] + bsum;
            }
        }
    }
}

// ---------------------------------------------------------------------------
// Kernel B: MFMA recurrence, one WG per batch (64 WGs), broadcast-B, with
// LANE-REDISTRIBUTED EPILOGUE (the R11 fix):
//   - MFMA phase unchanged from R11: A = interleaved U (register-resident,
//     128 VGPRs), B = h broadcast from LDS (uniform ds_read_b128), acc
//     zero-init; D columns identical across r.
//   - Exchange: r==0 lanes (4/wave) write their 4 f32x4 accs (the wave's 32
//     distinct (z,h~) preact pairs) to wave-private LDS sbuf[w] (256 B).
//     Same-wave DS ordering -> no barrier.
//   - Epilogue: lanes 0-31 each own ONE output o = 32w+lane: read float2
//     pair, add xz/xh (prefetched per-output, coalesced), sigmoid+tanh,
//     h state one float/lane, 4B out store, 2B LDS h store.
//     4 trans ops/wave/step instead of 32/thread (16x issue cut).
//   - xz/xh consumed in epilogue (not C-init); prefetched one step ahead.
// ---------------------------------------------------------------------------
__global__ __launch_bounds__(512, 2) void rec_mfma_kernel(
    const float* __restrict__ hidden0,
    const float* __restrict__ Uz,
    const float* __restrict__ Uh,
    const _Float16* __restrict__ xz16,
    float* __restrict__ out,
    float* __restrict__ h_final)
{
    const int b    = blockIdx.x;        // batch element (one per WG)
    const int tid  = threadIdx.x;
    const int w    = tid >> 6;          // wave 0..7
    const int lane = tid & 63;
    const int r    = lane & 15;         // A-row within tile / D col (replica)
    const int g    = lane >> 4;         // k-group / reg-group

    __shared__ __align__(16) _Float16 hbuf[2][256];   // h operand, dbuf
    __shared__ __align__(16) float    sbuf[8][64];    // per-wave exchange

    // ---- A-fragments: interleaved U, register-resident ----
    // tile i (global m = 4w+i): interleaved row 16m+rr <-> (rr&1?Uh:Uz)[8m+(rr>>1)]
    hf8 au[4][8];
    {
        const float* usrc = (r & 1) ? Uh : Uz;
        const int    hrow = r >> 1;
#pragma unroll
        for (int i = 0; i < 4; ++i) {
            const int m = 4 * w + i;
            const float* p0 = usrc + (size_t)(8 * m + hrow) * HID;
#pragma unroll
            for (int kt = 0; kt < 8; ++kt) {
                const float* p = p0 + kt * 32 + 8 * g;
                au[i][kt] = cvt8(*reinterpret_cast<const float4*>(p),
                                 *reinterpret_cast<const float4*>(p + 4));
            }
        }
    }

    // ---- init LDS h ----
    if (tid < 256) {
        hbuf[0][tid] = (_Float16)hidden0[b * HID + tid];
    }

    // ---- epilogue-lane state (lane < 32): output o = 32w + lane ----
    const int o = 32 * w + lane;        // valid/used only when lane < 32
    float hp = 0.0f;
    const _Float16* pxz = xz16 + (size_t)b * HID + o;
    const float*    pxh = out  + (size_t)b * HID + o;
    float*          pst = out  + (size_t)b * HID + o;
    float xz_cur = 0.0f, xh_cur = 0.0f, xz_nxt = 0.0f, xh_nxt = 0.0f;
    if (lane < 32) {
        hp     = hidden0[b * HID + o];
        xz_cur = (float)*pxz;           // t = 0
        xh_cur = *pxh;
        pxz += (size_t)BATCH * HID;
        pxh += (size_t)BATCH * HID;
    }
    __syncthreads();

#define REC_STEP(CUR, NXT)                                                     \
    {                                                                          \
        /* prefetch next step's xz/xh (coalesced, 2B+4B per epilogue lane) */  \
        if (lane < 32) {                                                       \
            xz_nxt = (float)*pxz;                                              \
            xh_nxt = *pxh;                                                     \
            pxz += (size_t)BATCH * HID;                                        \
            pxh += (size_t)BATCH * HID;                                        \
        }                                                                      \
        /* broadcast B-fragments: uniform address per g-group */               \
        hf8 bb[8];                                                             \
        _Pragma("unroll")                                                      \
        for (int kt = 0; kt < 8; ++kt) {                                       \
            bb[kt] = *reinterpret_cast<const hf8*>(                            \
                &hbuf[CUR][kt * 32 + 8 * g]);                                  \
        }                                                                      \
        f32x4 acc[4] = {f32x4{0,0,0,0}, f32x4{0,0,0,0},                        \
                        f32x4{0,0,0,0}, f32x4{0,0,0,0}};                       \
        _Pragma("unroll")                                                      \
        for (int kt = 0; kt < 8; ++kt) {                                       \
            _Pragma("unroll")                                                  \
            for (int i = 0; i < 4; ++i) {                                      \
                acc[i] = __builtin_amdgcn_mfma_f32_16x16x32_f16(               \
                    au[i][kt], bb[kt], acc[i], 0, 0, 0);                       \
            }                                                                  \
        }                                                                      \
        /* wave-private exchange: r==0 lanes publish 32 (z,h~) pairs */        \
        if (r == 0) {                                                          \
            _Pragma("unroll")                                                  \
            for (int i = 0; i < 4; ++i) {                                      \
                *reinterpret_cast<f32x4*>(&sbuf[w][i * 16 + g * 4]) = acc[i];  \
            }                                                                  \
        }                                                                      \
        /* epilogue: one output per lane (lanes 0-31) */                       \
        if (lane < 32) {                                                       \
            const float2 pr = *reinterpret_cast<const float2*>(                \
                &sbuf[w][2 * lane]);                                           \
            const float z  = fast_sigmoid(pr.x + xz_cur);                      \
            const float th = fast_tanh(pr.y + xh_cur);                         \
            hp = fmaf(z, th - hp, hp);                                         \
            *pst = hp;                                                         \
            pst += (size_t)BATCH * HID;                                        \
            hbuf[NXT][o] = (_Float16)hp;                                       \
        }                                                                      \
        xz_cur = xz_nxt;                                                       \
        xh_cur = xh_nxt;                                                       \
        __syncthreads();                                                       \
    }

    for (int t = 0; t < SEQ; t += 2) {
        REC_STEP(0, 1)
        REC_STEP(1, 0)
    }
#undef REC_STEP

    if (lane < 32) {
        h_final[(size_t)b * HID + o] = hp;
    }
}

extern "C" void kernel_launch(void* const* d_in, const int* in_sizes, int n_in,
                              void* d_out, int out_size, void* d_ws, size_t ws_size,
                              hipStream_t stream) {
    const float* x      = (const float*)d_in[0];
    const float* hidden = (const float*)d_in[1];
    const float* Wz     = (const float*)d_in[2];
    const float* bz     = (const float*)d_in[3];
    const float* Uz     = (const float*)d_in[4];
    const float* cz     = (const float*)d_in[5];
    const float* Wh     = (const float*)d_in[6];
    const float* bh     = (const float*)d_in[7];
    const float* Uh     = (const float*)d_in[8];
    const float* ch     = (const float*)d_in[9];

    float* out     = (float*)d_out;                        // [SEQ*BATCH*HID]
    float* h_final = out + (size_t)SEQ * BATCH * HID;      // [BATCH*HID]

    _Float16* xz16 = (_Float16*)d_ws;                               // 64 MiB
    _Float16* W16  = (_Float16*)((char*)d_ws + ((size_t)64 << 20)); // 256 KiB

    w16_kernel<<<512, 256, 0, stream>>>(Wz, Wh, W16);

    proj_mfma_kernel<<<(SEQ * BATCH) / 16, 256, 0, stream>>>(
        x, W16, bz, cz, bh, ch, xz16, out);

    rec_mfma_kernel<<<BATCH, 512, 0, stream>>>(
        hidden, Uz, Uh, xz16, out, h_final);
}

// Round 13
// 2163.173 us; speedup vs baseline: 1.2208x; 1.2208x over previous
//
#include <hip/hip_runtime.h>
#include <math.h>

#define SEQ   2048
#define BATCH 64
#define IN    256
#define HID   256
#define NBLK  (SEQ / 8)

typedef _Float16 hf2 __attribute__((ext_vector_type(2)));
typedef _Float16 hf4 __attribute__((ext_vector_type(4)));
typedef _Float16 hf8 __attribute__((ext_vector_type(8)));
typedef float    f32x4 __attribute__((ext_vector_type(4)));

static __device__ __forceinline__ float fast_sigmoid(float x) {
    return __builtin_amdgcn_rcpf(1.0f + __expf(-x));
}

static __device__ __forceinline__ float fast_tanh(float x) {
    const float e = __expf(-2.0f * x);
    return fmaf(2.0f, __builtin_amdgcn_rcpf(1.0f + e), -1.0f);
}

static __device__ __forceinline__ hf8 cvt8(const float4& a, const float4& b) {
    hf8 f;
    f[0] = (_Float16)a.x; f[1] = (_Float16)a.y;
    f[2] = (_Float16)a.z; f[3] = (_Float16)a.w;
    f[4] = (_Float16)b.x; f[5] = (_Float16)b.y;
    f[6] = (_Float16)b.z; f[7] = (_Float16)b.w;
    return f;
}

// Barrier with LDS-ordering only: NO vmcnt(0) drain (h stores and staging
// loads stay in flight). No sched_barrier pinning (R10 lesson).
static __device__ __forceinline__ void bar_lds() {
    asm volatile("s_waitcnt lgkmcnt(0)" ::: "memory");
    __builtin_amdgcn_s_barrier();
}

// ---------------------------------------------------------------------------
// Kernel 0: Wz,Wh fp32 -> W16 [512][256] fp16
// ---------------------------------------------------------------------------
__global__ __launch_bounds__(256) void w16_kernel(
    const float* __restrict__ Wz, const float* __restrict__ Wh,
    _Float16* __restrict__ W16)
{
    const int idx = blockIdx.x * 256 + threadIdx.x;
    const int row = idx >> 8;
    const int col = idx & 255;
    const float v = (row < 256) ? Wz[row * 256 + col] : Wh[(row - 256) * 256 + col];
    W16[idx] = (_Float16)v;
}

// ---------------------------------------------------------------------------
// Kernel A: input projections via mfma_f32_16x16x32_f16 (validated R4+).
// ---------------------------------------------------------------------------
__global__ __launch_bounds__(256) void proj_mfma_kernel(
    const float* __restrict__ x,
    const _Float16* __restrict__ W16,
    const float* __restrict__ bz, const float* __restrict__ cz,
    const float* __restrict__ bh, const float* __restrict__ ch,
    _Float16* __restrict__ xz16,
    float* __restrict__ xh_out)
{
    const int tid  = threadIdx.x;
    const int lane = tid & 63;
    const int w    = tid >> 6;
    const int m0   = blockIdx.x * 16;
    const int col0 = w * 128;

    const int r = lane & 15;
    const int g = lane >> 4;

    f32x4 acc[8] = {f32x4{0,0,0,0}, f32x4{0,0,0,0}, f32x4{0,0,0,0}, f32x4{0,0,0,0},
                    f32x4{0,0,0,0}, f32x4{0,0,0,0}, f32x4{0,0,0,0}, f32x4{0,0,0,0}};

    const float*    xrow  = x   + (size_t)(m0 + r) * IN + g * 8;
    const _Float16* wbase = W16 + (size_t)(col0 + r) * IN + g * 8;

#pragma unroll
    for (int kt = 0; kt < 8; ++kt) {
        const float4 xa = *reinterpret_cast<const float4*>(xrow + kt * 32);
        const float4 xb = *reinterpret_cast<const float4*>(xrow + kt * 32 + 4);
        const hf8 a = cvt8(xa, xb);
#pragma unroll
        for (int t = 0; t < 8; ++t) {
            const hf8 bfrag = *reinterpret_cast<const hf8*>(
                wbase + (size_t)t * 16 * IN + kt * 32);
            acc[t] = __builtin_amdgcn_mfma_f32_16x16x32_f16(a, bfrag, acc[t], 0, 0, 0);
        }
    }

    if (w < 2) {
#pragma unroll
        for (int t = 0; t < 8; ++t) {
            const int c = col0 + t * 16 + r;
            const float bsum = bz[c] + cz[c];
#pragma unroll
            for (int reg = 0; reg < 4; ++reg) {
                const int m = m0 + 4 * g + reg;
                xz16[(size_t)m * HID + c] = (_Float16)(acc[t][reg] + bsum);
            }
        }
    } else {
#pragma unroll
        for (int t = 0; t < 8; ++t) {
            const int c = col0 - 256 + t * 16 + r;
            const float bsum = bh[c] + ch[c];
#pragma unroll
            for (int reg = 0; reg < 4; ++reg) {
                const int m = m0 + 4 * g + reg;
                xh_out[(size_t)m * HID + c] = acc[t][reg] + bsum;
            }
        }
    }
}

// ---------------------------------------------------------------------------
// Kernel B: MFMA recurrence, one WG per batch (64 WGs), broadcast-B,
// lane-redistributed epilogue (R12), plus (R13):
//   - xz/xh staged in LDS in 8-step blocks, double-buffered, register-relayed
//     with 2-block prefetch distance -> per-step reads are pure LDS; the only
//     vmcnt wait is one vmcnt(<=8) per 8 steps (free).
//   - per-step barrier = lgkmcnt(0) + raw s_barrier: NO vmcnt(0) drain ->
//     h stores fire-and-forget, staging loads in flight across steps.
// Staging hazard check: loads for block j+2 read out[] rows [8j+16, 8j+24),
// h stores during blocks j..j+1 write rows [8j, 8j+16) -> disjoint, and
// reads always run ahead of writes.
// ---------------------------------------------------------------------------
__global__ __launch_bounds__(512, 2) void rec_mfma_kernel(
    const float* __restrict__ hidden0,
    const float* __restrict__ Uz,
    const float* __restrict__ Uh,
    const _Float16* __restrict__ xz16,
    float* __restrict__ out,
    float* __restrict__ h_final)
{
    const int b    = blockIdx.x;        // batch element (one per WG)
    const int tid  = threadIdx.x;
    const int w    = tid >> 6;          // wave 0..7
    const int lane = tid & 63;
    const int r    = lane & 15;         // A-row within tile / D col (replica)
    const int g    = lane >> 4;         // k-group / reg-group

    __shared__ __align__(16) _Float16 hbuf[2][256];        // h operand, dbuf
    __shared__ __align__(16) float    sbuf[8][64];         // per-wave exchange
    __shared__ __align__(16) _Float16 xzs[2][8][256];      // xz block stage
    __shared__ __align__(16) float    xhs[2][8][256];      // xh block stage

    // ---- A-fragments: interleaved U, register-resident (128 VGPRs) ----
    hf8 au[4][8];
    {
        const float* usrc = (r & 1) ? Uh : Uz;
        const int    hrow = r >> 1;
#pragma unroll
        for (int i = 0; i < 4; ++i) {
            const int m = 4 * w + i;
            const float* p0 = usrc + (size_t)(8 * m + hrow) * HID;
#pragma unroll
            for (int kt = 0; kt < 8; ++kt) {
                const float* p = p0 + kt * 32 + 8 * g;
                au[i][kt] = cvt8(*reinterpret_cast<const float4*>(p),
                                 *reinterpret_cast<const float4*>(p + 4));
            }
        }
    }

    // ---- init LDS h ----
    if (tid < 256) {
        hbuf[0][tid] = (_Float16)hidden0[b * HID + tid];
    }

    // ---- epilogue-lane state (lane < 32): output o = 32w + lane ----
    const int o = 32 * w + lane;        // used only when lane < 32
    float hp = 0.0f;
    float* pst = out + (size_t)b * HID + o;
    if (lane < 32) {
        hp = hidden0[b * HID + o];
    }

    // ---- x-staging: thread (srow, chunk) relays 4 halves + 4 floats ----
    const int srow = tid >> 6;          // 0..7 (step within block)
    const int scol = (tid & 63) * 4;    // 4-elem chunk
    hf4   rz;
    f32x4 rh;
    {
        // block 0 -> LDS directly
        const size_t a0 = ((size_t)srow * BATCH + b) * HID + scol;
        const hf4   z0 = *reinterpret_cast<const hf4*>(xz16 + a0);
        const f32x4 h0 = *reinterpret_cast<const f32x4*>(out + a0);
        *reinterpret_cast<hf4*>(&xzs[0][srow][scol])   = z0;
        *reinterpret_cast<f32x4*>(&xhs[0][srow][scol]) = h0;
        // block 1 -> regs
        const size_t a1 = ((size_t)(8 + srow) * BATCH + b) * HID + scol;
        rz = *reinterpret_cast<const hf4*>(xz16 + a1);
        rh = *reinterpret_cast<const f32x4*>(out + a1);
    }
    __syncthreads();

    for (int j = 0; j < NBLK; ++j) {
        const int jb = j & 1;
#pragma unroll
        for (int s = 0; s < 8; ++s) {
            // staged x reads (pure LDS)
            float xzc = 0.0f, xhc = 0.0f;
            if (lane < 32) {
                xzc = (float)xzs[jb][s][o];
                xhc = xhs[jb][s][o];
            }
            // broadcast B-fragments (uniform addr per g-group)
            hf8 bb[8];
#pragma unroll
            for (int kt = 0; kt < 8; ++kt) {
                bb[kt] = *reinterpret_cast<const hf8*>(
                    &hbuf[s & 1][kt * 32 + 8 * g]);
            }
            f32x4 acc[4] = {f32x4{0,0,0,0}, f32x4{0,0,0,0},
                            f32x4{0,0,0,0}, f32x4{0,0,0,0}};
#pragma unroll
            for (int kt = 0; kt < 8; ++kt) {
#pragma unroll
                for (int i = 0; i < 4; ++i) {
                    acc[i] = __builtin_amdgcn_mfma_f32_16x16x32_f16(
                        au[i][kt], bb[kt], acc[i], 0, 0, 0);
                }
            }
            // wave-private exchange (same-wave DS ordering, no barrier)
            if (r == 0) {
#pragma unroll
                for (int i = 0; i < 4; ++i) {
                    *reinterpret_cast<f32x4*>(&sbuf[w][i * 16 + g * 4]) = acc[i];
                }
            }
            // epilogue: one output per lane
            if (lane < 32) {
                const float2 pr = *reinterpret_cast<const float2*>(
                    &sbuf[w][2 * lane]);
                const float z  = fast_sigmoid(pr.x + xzc);
                const float th = fast_tanh(pr.y + xhc);
                hp = fmaf(z, th - hp, hp);
                *pst = hp;                       // fire-and-forget HBM store
                pst += (size_t)BATCH * HID;
                hbuf[(s + 1) & 1][o] = (_Float16)hp;
            }
            // block boundary: relay regs -> LDS, issue loads 2 blocks ahead
            if (s == 7 && j + 1 < NBLK) {
                *reinterpret_cast<hf4*>(&xzs[jb ^ 1][srow][scol])   = rz;
                *reinterpret_cast<f32x4*>(&xhs[jb ^ 1][srow][scol]) = rh;
                int trow = 8 * (j + 2) + srow;
                if (trow >= SEQ) trow = SEQ - 1;     // tail clamp (unused)
                const size_t an = ((size_t)trow * BATCH + b) * HID + scol;
                rz = *reinterpret_cast<const hf4*>(xz16 + an);
                rh = *reinterpret_cast<const f32x4*>(out + an);
            }
            bar_lds();
        }
    }

    if (lane < 32) {
        h_final[(size_t)b * HID + o] = hp;
    }
}

extern "C" void kernel_launch(void* const* d_in, const int* in_sizes, int n_in,
                              void* d_out, int out_size, void* d_ws, size_t ws_size,
                              hipStream_t stream) {
    const float* x      = (const float*)d_in[0];
    const float* hidden = (const float*)d_in[1];
    const float* Wz     = (const float*)d_in[2];
    const float* bz     = (const float*)d_in[3];
    const float* Uz     = (const float*)d_in[4];
    const float* cz     = (const float*)d_in[5];
    const float* Wh     = (const float*)d_in[6];
    const float* bh     = (const float*)d_in[7];
    const float* Uh     = (const float*)d_in[8];
    const float* ch     = (const float*)d_in[9];

    float* out     = (float*)d_out;                        // [SEQ*BATCH*HID]
    float* h_final = out + (size_t)SEQ * BATCH * HID;      // [BATCH*HID]

    _Float16* xz16 = (_Float16*)d_ws;                               // 64 MiB
    _Float16* W16  = (_Float16*)((char*)d_ws + ((size_t)64 << 20)); // 256 KiB

    w16_kernel<<<512, 256, 0, stream>>>(Wz, Wh, W16);

    proj_mfma_kernel<<<(SEQ * BATCH) / 16, 256, 0, stream>>>(
        x, W16, bz, cz, bh, ch, xz16, out);

    rec_mfma_kernel<<<BATCH, 512, 0, stream>>>(
        hidden, Uz, Uh, xz16, out, h_final);
}

// Round 14
// 2080.661 us; speedup vs baseline: 1.2692x; 1.0397x over previous
//
#include <hip/hip_runtime.h>
#include <math.h>

#define SEQ   2048
#define BATCH 64
#define IN    256
#define HID   256
#define NBLK  (SEQ / 8)

typedef _Float16 hf2 __attribute__((ext_vector_type(2)));
typedef _Float16 hf4 __attribute__((ext_vector_type(4)));
typedef _Float16 hf8 __attribute__((ext_vector_type(8)));
typedef float    f32x2 __attribute__((ext_vector_type(2)));
typedef float    f32x4 __attribute__((ext_vector_type(4)));

static __device__ __forceinline__ float fast_sigmoid(float x) {
    return __builtin_amdgcn_rcpf(1.0f + __expf(-x));
}

static __device__ __forceinline__ float fast_tanh(float x) {
    const float e = __expf(-2.0f * x);
    return fmaf(2.0f, __builtin_amdgcn_rcpf(1.0f + e), -1.0f);
}

static __device__ __forceinline__ hf8 cvt8(const float4& a, const float4& b) {
    hf8 f;
    f[0] = (_Float16)a.x; f[1] = (_Float16)a.y;
    f[2] = (_Float16)a.z; f[3] = (_Float16)a.w;
    f[4] = (_Float16)b.x; f[5] = (_Float16)b.y;
    f[6] = (_Float16)b.z; f[7] = (_Float16)b.w;
    return f;
}

// LDS-ordering barrier: no vmcnt(0) drain (R13 win), no sched_barrier pin.
static __device__ __forceinline__ void bar_lds() {
    asm volatile("s_waitcnt lgkmcnt(0)" ::: "memory");
    __builtin_amdgcn_s_barrier();
}

// ---------------------------------------------------------------------------
// Kernel 0: Wz,Wh fp32 -> W16 [512][256] fp16
// ---------------------------------------------------------------------------
__global__ __launch_bounds__(256) void w16_kernel(
    const float* __restrict__ Wz, const float* __restrict__ Wh,
    _Float16* __restrict__ W16)
{
    const int idx = blockIdx.x * 256 + threadIdx.x;
    const int row = idx >> 8;
    const int col = idx & 255;
    const float v = (row < 256) ? Wz[row * 256 + col] : Wh[(row - 256) * 256 + col];
    W16[idx] = (_Float16)v;
}

// ---------------------------------------------------------------------------
// Kernel A: input projections via mfma_f32_16x16x32_f16 (validated R4+).
// ---------------------------------------------------------------------------
__global__ __launch_bounds__(256) void proj_mfma_kernel(
    const float* __restrict__ x,
    const _Float16* __restrict__ W16,
    const float* __restrict__ bz, const float* __restrict__ cz,
    const float* __restrict__ bh, const float* __restrict__ ch,
    _Float16* __restrict__ xz16,
    float* __restrict__ xh_out)
{
    const int tid  = threadIdx.x;
    const int lane = tid & 63;
    const int w    = tid >> 6;
    const int m0   = blockIdx.x * 16;
    const int col0 = w * 128;

    const int r = lane & 15;
    const int g = lane >> 4;

    f32x4 acc[8] = {f32x4{0,0,0,0}, f32x4{0,0,0,0}, f32x4{0,0,0,0}, f32x4{0,0,0,0},
                    f32x4{0,0,0,0}, f32x4{0,0,0,0}, f32x4{0,0,0,0}, f32x4{0,0,0,0}};

    const float*    xrow  = x   + (size_t)(m0 + r) * IN + g * 8;
    const _Float16* wbase = W16 + (size_t)(col0 + r) * IN + g * 8;

#pragma unroll
    for (int kt = 0; kt < 8; ++kt) {
        const float4 xa = *reinterpret_cast<const float4*>(xrow + kt * 32);
        const float4 xb = *reinterpret_cast<const float4*>(xrow + kt * 32 + 4);
        const hf8 a = cvt8(xa, xb);
#pragma unroll
        for (int t = 0; t < 8; ++t) {
            const hf8 bfrag = *reinterpret_cast<const hf8*>(
                wbase + (size_t)t * 16 * IN + kt * 32);
            acc[t] = __builtin_amdgcn_mfma_f32_16x16x32_f16(a, bfrag, acc[t], 0, 0, 0);
        }
    }

    if (w < 2) {
#pragma unroll
        for (int t = 0; t < 8; ++t) {
            const int c = col0 + t * 16 + r;
            const float bsum = bz[c] + cz[c];
#pragma unroll
            for (int reg = 0; reg < 4; ++reg) {
                const int m = m0 + 4 * g + reg;
                xz16[(size_t)m * HID + c] = (_Float16)(acc[t][reg] + bsum);
            }
        }
    } else {
#pragma unroll
        for (int t = 0; t < 8; ++t) {
            const int c = col0 - 256 + t * 16 + r;
            const float bsum = bh[c] + ch[c];
#pragma unroll
            for (int reg = 0; reg < 4; ++reg) {
                const int m = m0 + 4 * g + reg;
                xh_out[(size_t)m * HID + c] = acc[t][reg] + bsum;
            }
        }
    }
}

// ---------------------------------------------------------------------------
// Kernel B: MFMA recurrence. One WG per batch, now 1024 threads = 16 waves
// (4 waves/SIMD — the R14 change: TLP to hide LDS latency chains that 2
// waves/SIMD left exposed in R13).
//   - Wave w owns M-tiles {2w, 2w+1} of interleaved U (64 VGPRs) -> 16
//     MFMA/wave/step, per-SIMD issue unchanged (64 MFMA ~ 310 cy).
//   - bb-fragments read INSIDE the kt loop (short live range; keeps
//     VGPR <= 128, the hard cap for a 1024-thread WG).
//   - sbuf = flat float[512]: preact of interleaved row idx at sbuf[idx];
//     epilogue lane<16 reads float2 at 2*o (o = 16w+lane), same-wave order.
//   - x-staging (R13), lgkm-only barrier (R13), fire-and-forget h stores.
// ---------------------------------------------------------------------------
__global__ __launch_bounds__(1024, 1) void rec_mfma_kernel(
    const float* __restrict__ hidden0,
    const float* __restrict__ Uz,
    const float* __restrict__ Uh,
    const _Float16* __restrict__ xz16,
    float* __restrict__ out,
    float* __restrict__ h_final)
{
    const int b    = blockIdx.x;        // batch element (one per WG)
    const int tid  = threadIdx.x;
    const int w    = tid >> 6;          // wave 0..15
    const int lane = tid & 63;
    const int r    = lane & 15;         // A-row within tile / D col (replica)
    const int g    = lane >> 4;         // k-group / reg-group

    __shared__ __align__(16) _Float16 hbuf[2][256];        // h operand, dbuf
    __shared__ __align__(16) float    sbuf[512];           // preact exchange
    __shared__ __align__(16) _Float16 xzs[2][8][256];      // xz block stage
    __shared__ __align__(16) float    xhs[2][8][256];      // xh block stage

    // ---- A-fragments: interleaved U, tiles {2w, 2w+1} (64 VGPRs) ----
    hf8 au[2][8];
    {
        const float* usrc = (r & 1) ? Uh : Uz;
        const int    hrow = r >> 1;
#pragma unroll
        for (int i = 0; i < 2; ++i) {
            const int m = 2 * w + i;
            const float* p0 = usrc + (size_t)(8 * m + hrow) * HID;
#pragma unroll
            for (int kt = 0; kt < 8; ++kt) {
                const float* p = p0 + kt * 32 + 8 * g;
                au[i][kt] = cvt8(*reinterpret_cast<const float4*>(p),
                                 *reinterpret_cast<const float4*>(p + 4));
            }
        }
    }

    // ---- init LDS h ----
    if (tid < 256) {
        hbuf[0][tid] = (_Float16)hidden0[b * HID + tid];
    }

    // ---- epilogue-lane state (lane < 16): output o = 16w + lane ----
    const int o = 16 * w + (lane & 15);
    float hp = 0.0f;
    float* pst = out + (size_t)b * HID + o;
    if (lane < 16) {
        hp = hidden0[b * HID + o];
    }

    // ---- x-staging: 1024 threads; thread (srow, 2-elem chunk) ----
    const int srow = tid >> 7;           // 0..7 (step within block)
    const int scol = (tid & 127) * 2;    // 2-elem chunk
    hf2   rz;
    f32x2 rh;
    {
        const size_t a0 = ((size_t)srow * BATCH + b) * HID + scol;
        *reinterpret_cast<hf2*>(&xzs[0][srow][scol]) =
            *reinterpret_cast<const hf2*>(xz16 + a0);
        *reinterpret_cast<f32x2*>(&xhs[0][srow][scol]) =
            *reinterpret_cast<const f32x2*>(out + a0);
        const size_t a1 = ((size_t)(8 + srow) * BATCH + b) * HID + scol;
        rz = *reinterpret_cast<const hf2*>(xz16 + a1);
        rh = *reinterpret_cast<const f32x2*>(out + a1);
    }
    __syncthreads();

    for (int j = 0; j < NBLK; ++j) {
        const int jb = j & 1;
#pragma unroll
        for (int s = 0; s < 8; ++s) {
            // staged x reads (pure LDS)
            float xzc = 0.0f, xhc = 0.0f;
            if (lane < 16) {
                xzc = (float)xzs[jb][s][o];
                xhc = xhs[jb][s][o];
            }
            // MFMA with bb read inside the loop (short live range)
            f32x4 acc0{0, 0, 0, 0}, acc1{0, 0, 0, 0};
#pragma unroll
            for (int kt = 0; kt < 8; ++kt) {
                const hf8 bb = *reinterpret_cast<const hf8*>(
                    &hbuf[s & 1][kt * 32 + 8 * g]);
                acc0 = __builtin_amdgcn_mfma_f32_16x16x32_f16(
                    au[0][kt], bb, acc0, 0, 0, 0);
                acc1 = __builtin_amdgcn_mfma_f32_16x16x32_f16(
                    au[1][kt], bb, acc1, 0, 0, 0);
            }
            // exchange: r==0 lanes publish preacts (flat idx = interleaved row)
            if (r == 0) {
                *reinterpret_cast<f32x4*>(&sbuf[(2 * w) * 16 + 4 * g])     = acc0;
                *reinterpret_cast<f32x4*>(&sbuf[(2 * w + 1) * 16 + 4 * g]) = acc1;
            }
            // epilogue: one output per lane (lanes 0-15), same-wave ordering
            if (lane < 16) {
                const f32x2 pr = *reinterpret_cast<const f32x2*>(&sbuf[2 * o]);
                const float z  = fast_sigmoid(pr[0] + xzc);
                const float th = fast_tanh(pr[1] + xhc);
                hp = fmaf(z, th - hp, hp);
                *pst = hp;                       // fire-and-forget HBM store
                pst += (size_t)BATCH * HID;
                hbuf[(s + 1) & 1][o] = (_Float16)hp;
            }
            // block boundary: relay regs -> LDS, issue loads 2 blocks ahead
            if (s == 7 && j + 1 < NBLK) {
                *reinterpret_cast<hf2*>(&xzs[jb ^ 1][srow][scol])   = rz;
                *reinterpret_cast<f32x2*>(&xhs[jb ^ 1][srow][scol]) = rh;
                int trow = 8 * (j + 2) + srow;
                if (trow >= SEQ) trow = SEQ - 1;     // tail clamp (unused)
                const size_t an = ((size_t)trow * BATCH + b) * HID + scol;
                rz = *reinterpret_cast<const hf2*>(xz16 + an);
                rh = *reinterpret_cast<const f32x2*>(out + an);
            }
            bar_lds();
        }
    }

    if (lane < 16) {
        h_final[(size_t)b * HID + o] = hp;
    }
}

extern "C" void kernel_launch(void* const* d_in, const int* in_sizes, int n_in,
                              void* d_out, int out_size, void* d_ws, size_t ws_size,
                              hipStream_t stream) {
    const float* x      = (const float*)d_in[0];
    const float* hidden = (const float*)d_in[1];
    const float* Wz     = (const float*)d_in[2];
    const float* bz     = (const float*)d_in[3];
    const float* Uz     = (const float*)d_in[4];
    const float* cz     = (const float*)d_in[5];
    const float* Wh     = (const float*)d_in[6];
    const float* bh     = (const float*)d_in[7];
    const float* Uh     = (const float*)d_in[8];
    const float* ch     = (const float*)d_in[9];

    float* out     = (float*)d_out;                        // [SEQ*BATCH*HID]
    float* h_final = out + (size_t)SEQ * BATCH * HID;      // [BATCH*HID]

    _Float16* xz16 = (_Float16*)d_ws;                               // 64 MiB
    _Float16* W16  = (_Float16*)((char*)d_ws + ((size_t)64 << 20)); // 256 KiB

    w16_kernel<<<512, 256, 0, stream>>>(Wz, Wh, W16);

    proj_mfma_kernel<<<(SEQ * BATCH) / 16, 256, 0, stream>>>(
        x, W16, bz, cz, bh, ch, xz16, out);

    rec_mfma_kernel<<<BATCH, 1024, 0, stream>>>(
        hidden, Uz, Uh, xz16, out, h_final);
}